// Round 4
// baseline (814.925 us; speedup 1.0000x reference)
//
#include <hip/hip_runtime.h>
#include <math.h>

// Fused WaveNet-ish encoder, v9: retiled waves 4mg x 4ng (64o x 32t per wave).
// Theory: v8's dominant pipe was LDS (2048 ds_read_b128/CU/layer, each feeding
// only 2 MFMAs; 8 mg-waves read B redundantly). v9's wave computes two 32x32
// o-tiles from ONE B-fragment read -> 4 MFMAs per B-read, LDS reads 4x down,
// mul8 2x down, same MFMA count, same 32-reg accumulator. A-load instruction
// count doubles but unique bytes unchanged (4 same-mg waves share via L1/L2).
// Keeps v8's anti-spill discipline: no pipeline arrays, unroll<=2, no
// runtime-indexed arrays, single accumulator w/ in-chain lo-compensation.

#define BATCH 256
#define INCH  1024
#define HID   256
#define TLEN  128
#define CTXN  16
#define NLAY  8
#define LEAKF 0.2f
#define EPSF  1e-8f
#define SLO5  0.03125f   // 2^-5
#define SHI5  32.0f      // 2^5

typedef _Float16 f16;
typedef f16 f16x4 __attribute__((ext_vector_type(4)));
typedef f16 f16x8 __attribute__((ext_vector_type(8)));
typedef float f32x16 __attribute__((ext_vector_type(16)));

#define HT_STRIDE 264                    // halfs per row (528B, rows 16B-aligned)
#define HT_HALFS  (TLEN * HT_STRIDE)     // 33792
#define SCR_STRIDE 132
#define WS_CONV (NLAY*HID*2*HID)
#define WS_PROJ (HID*INCH)
#define WS_TOT  (WS_CONV + WS_PROJ)
#define LDS_BYTES (HT_HALFS*2 + (8*SCR_STRIDE + TLEN + 16)*4)   // 72384

#define MFMA32(A,B,C) __builtin_amdgcn_mfma_f32_32x32x16_f16(A,B,C,0,0,0)
// swizzle: bits from t>>3 (intra-32 groups) AND t>>5 (staging quarter groups)
#define SW(t) (((((t)>>3)&3)<<3) ^ ((((t)>>5)&3)<<4))

static __device__ __forceinline__ f16x8 mul8(f16x8 v, f16 s) {
    f16x8 r;
    #pragma unroll
    for (int i = 0; i < 8; ++i) r[i] = v[i] * s;
    return r;
}

__global__ __launch_bounds__(256)
void prep_weights(const float* __restrict__ conv_w,
                  const float* __restrict__ proj_w,
                  f16* __restrict__ wh, f16* __restrict__ wlo)
{
    const int i = blockIdx.x * blockDim.x + threadIdx.x;
    if (i >= WS_TOT) return;
    float v; int dst;
    if (i < WS_CONV) {
        // src conv_w[l][o][ii][kk] -> dst [l][o][kk][ii]
        const int kk = i & 1, ii = (i >> 1) & (HID-1), o = (i >> 9) & (HID-1), l = i >> 17;
        v = conv_w[i];
        dst = ((l*HID + o)*2 + kk)*HID + ii;
    } else {
        v = proj_w[i - WS_CONV];
        dst = i;                         // proj [o][i] after conv region
    }
    const f16 hi = (f16)v;
    wh[dst]  = hi;
    wlo[dst] = (f16)((v - (float)hi) * SHI5);
}

__global__ __launch_bounds__(1024, 4)
void wavenet9(const float* __restrict__ x,
              const f16*   __restrict__ wh,
              const f16*   __restrict__ wlo,
              const float* __restrict__ proj_b,
              const float* __restrict__ conv_b,
              const float* __restrict__ ev_w,
              const float* __restrict__ ev_b,
              const float* __restrict__ sw_w,
              const float* __restrict__ sw_b,
              float* __restrict__ out)
{
    extern __shared__ char ldsb[];
    f16*   Ht   = (f16*)ldsb;                       // [128][264] swizzled, f16
    float* scr  = (float*)(ldsb + HT_HALFS*2);      // [8][132]
    float* attn = scr + 8*SCR_STRIDE;               // [128]
    float* redf = attn + TLEN;                      // [16]

    const int b    = blockIdx.x;
    const int tid  = threadIdx.x;
    const int lane = tid & 63;
    const int wv   = __builtin_amdgcn_readfirstlane(tid >> 6);  // 0..15
    const int mg   = wv & 3;           // o-tile pair: ob..ob+63
    const int ng   = wv >> 2;          // t-tile: tb..tb+31
    const int ob   = mg << 6;
    const int tb   = ng << 5;
    const int col  = lane & 31;
    const int half = lane >> 5;
    const int t0   = tb + col;                       // this lane's t (fixed)
    const int sw0  = SW(t0);
    const int ro0  = t0*HT_STRIDE;

    f32x16 C[2];
    const f16x8 z8  = (f16x8)(f16)0.f;
    const f16   lo5 = (f16)SLO5;

    // ================= 1x1 projection 1024 -> 256 =================
    C[0] = (f32x16)0.f; C[1] = (f32x16)0.f;
    const f16* ph = wh  + WS_CONV;
    const f16* pl = wlo + WS_CONV;
    const float* xb = x + (size_t)b * INCH * TLEN;
    const int sr = tid >> 2, stq = tid & 3;   // stage: row in chunk, t-quarter

    #pragma unroll 1
    for (int c = 0; c < 4; ++c) {
        if (c) __syncthreads();          // previous chunk's B-reads complete
        {   // load + stage (transient registers only)
            const float* xr = xb + (size_t)(c*256 + sr) * TLEN + stq*32;
            #pragma unroll
            for (int u = 0; u < 8; ++u) {
                const float4 v4 = *(const float4*)(xr + u*4);
                const float vv[4] = {v4.x, v4.y, v4.z, v4.w};
                #pragma unroll
                for (int e = 0; e < 4; ++e) {
                    const int t = stq*32 + u*4 + e;
                    const int p = t*HT_STRIDE + (((sr & ~7) ^ SW(t)) | (sr & 7));
                    Ht[p] = (f16)vv[e];
                }
            }
        }
        __syncthreads();
        #pragma unroll 2
        for (int ks = 0; ks < 16; ++ks) {
            const int kloc = ks*16 + half*8;
            const f16x8 Bh = *(const f16x8*)(Ht + ro0 + (kloc ^ sw0));
            const f16x8 Bl = mul8(Bh, lo5);
            #pragma unroll
            for (int mo = 0; mo < 2; ++mo) {
                const size_t ao = (size_t)(ob + mo*32 + col)*INCH + c*256 + kloc;
                C[mo] = MFMA32(*(const f16x8*)(ph + ao), Bh, C[mo]);
                C[mo] = MFMA32(*(const f16x8*)(pl + ao), Bl, C[mo]);
            }
        }
    }
    __syncthreads();   // all B-reads done; Ht free for h
    #pragma unroll
    for (int mo = 0; mo < 2; ++mo) {
        const int obm = ob + mo*32;
        #pragma unroll
        for (int q = 0; q < 4; ++q) {
            const float4 bb = *(const float4*)(proj_b + obm + 8*q + 4*half);
            const float bv[4] = {bb.x, bb.y, bb.z, bb.w};
            f16x4 h4;
            #pragma unroll
            for (int s = 0; s < 4; ++s)
                h4[s] = (f16)(C[mo][q*4+s] + bv[s]);
            *(f16x4*)(Ht + ro0 + ((obm + 8*q) ^ sw0) + 4*half) = h4;
        }
    }
    __syncthreads();

    // ================= 8 dilated residual layers (in place in Ht) ==========
    #pragma unroll 1
    for (int l = 0; l < NLAY; ++l) {
        const int d = (l < 7) ? (1 << l) : 1;   // 1,2,4,8,16,32,64,1
        C[0] = (f32x16)0.f; C[1] = (f32x16)0.f;
        const f16* wA = wh  + (size_t)l*HID*2*HID;   // [o][kk][256]
        const f16* wL = wlo + (size_t)l*HID*2*HID;
        int r1 = t0 + d;
        const bool oob1 = r1 >= TLEN;
        if (oob1) r1 = TLEN-1;
        const int ro1 = r1*HT_STRIDE, sw1 = SW(r1);
        const int ab0 = (ob      + col)*2*HID + half*8;
        const int ab1 = (ob + 32 + col)*2*HID + half*8;
        #pragma unroll 2
        for (int ks = 0; ks < 16; ++ks) {
            const int k = ks*16;
            const int kh = k + half*8;
            // B fragments: one read each, feed BOTH mo tiles
            const f16x8 B0 = *(const f16x8*)(Ht + ro0 + (kh ^ sw0));
            f16x8 B1 = *(const f16x8*)(Ht + ro1 + (kh ^ sw1));
            if (oob1) B1 = z8;
            const f16x8 B0l = mul8(B0, lo5);
            const f16x8 B1l = mul8(B1, lo5);
            #pragma unroll
            for (int mo = 0; mo < 2; ++mo) {
                const int ab = mo ? ab1 : ab0;
                const f16x8 Ah0 = *(const f16x8*)(wA + ab + k);
                const f16x8 Al0 = *(const f16x8*)(wL + ab + k);
                const f16x8 Ah1 = *(const f16x8*)(wA + ab + HID + k);
                const f16x8 Al1 = *(const f16x8*)(wL + ab + HID + k);
                C[mo] = MFMA32(Ah0, B0,  C[mo]);
                C[mo] = MFMA32(Al0, B0l, C[mo]);
                C[mo] = MFMA32(Ah1, B1,  C[mo]);
                C[mo] = MFMA32(Al1, B1l, C[mo]);
            }
        }
        // ---- epilogue: bias + leaky + skip + sumsq ----
        float ps = 0.f;
        #pragma unroll
        for (int mo = 0; mo < 2; ++mo) {
            const int obm = ob + mo*32;
            #pragma unroll
            for (int q = 0; q < 4; ++q) {
                const float4 bb = *(const float4*)(conv_b + l*HID + obm + 8*q + 4*half);
                const float bv[4] = {bb.x, bb.y, bb.z, bb.w};
                const int p = ro0 + ((obm + 8*q) ^ sw0) + 4*half;
                const f16x4 sh = *(const f16x4*)(Ht + p);
                #pragma unroll
                for (int s = 0; s < 4; ++s) {
                    float y = C[mo][q*4+s] + bv[s];
                    y = y > 0.f ? y : LEAKF * y;
                    const float v = y + (float)sh[s];
                    C[mo][q*4+s] = v;
                    ps = fmaf(v, v, ps);
                }
            }
        }
        ps += __shfl_xor(ps, 32);          // combine o-halves (same t)
        if (lane < 32)
            scr[mg*SCR_STRIDE + t0] = ps;
        __syncthreads();   // all conv/skip reads done + scr complete
        float s = 0.f;
        #pragma unroll
        for (int g = 0; g < 4; ++g) s += scr[g*SCR_STRIDE + t0];
        const float inv = 1.f / (sqrtf(s) + EPSF);
        #pragma unroll
        for (int mo = 0; mo < 2; ++mo) {
            const int obm = ob + mo*32;
            #pragma unroll
            for (int q = 0; q < 4; ++q) {
                f16x4 h4;
                #pragma unroll
                for (int s2 = 0; s2 < 4; ++s2)
                    h4[s2] = (f16)(C[mo][q*4+s2] * inv);
                *(f16x4*)(Ht + ro0 + ((obm + 8*q) ^ sw0) + 4*half) = h4;
            }
        }
        __syncthreads();
    }

    // ================= switch head -> relu -> argmax =================
    {
        const int t = tid & 127, og = tid >> 7;
        const int sw = SW(t);
        float s = 0.f;
        #pragma unroll
        for (int q = 0; q < 4; ++q) {
            const int grp = og*32 + q*8;
            const f16x8 hv = *(const f16x8*)(Ht + t*HT_STRIDE + (grp ^ sw));
            const float* swp = sw_w + grp;
            #pragma unroll
            for (int j = 0; j < 8; ++j)
                s = fmaf(swp[j], (float)hv[j], s);
        }
        scr[og*SCR_STRIDE + t] = s;
    }
    __syncthreads();
    if (tid < TLEN) {
        float s = sw_b[0];
        #pragma unroll
        for (int g = 0; g < 8; ++g) s += scr[g*SCR_STRIDE + tid];
        attn[tid] = fmaxf(s, 0.f);
    }
    __syncthreads();
    if (tid < 64) {
        float v = attn[lane]; int bi = lane;
        const float v2 = attn[lane + 64];
        if (v2 > v) { v = v2; bi = lane + 64; }
        #pragma unroll
        for (int off = 32; off > 0; off >>= 1) {
            const float ov = __shfl_down(v, off);
            const int   oi = __shfl_down(bi, off);
            if (ov > v || (ov == v && oi < bi)) { v = ov; bi = oi; }
        }
        if (lane == 0) { redf[0] = v; ((int*)redf)[1] = bi; }
    }
    __syncthreads();
    const float bestv = redf[0];
    const int   bidx  = ((const int*)redf)[1];
    const int   swb   = SW(bidx);

    // event head: wave wv computes ctx=wv from h[:, bidx]
    {
        float s = 0.f;
        #pragma unroll
        for (int q = 0; q < 4; ++q) {
            const int o = lane + 64*q;
            const int p = bidx*HT_STRIDE + (((o & ~7) ^ swb) | (o & 7));
            s = fmaf(ev_w[wv*HID + o], (float)Ht[p], s);
        }
        #pragma unroll
        for (int off = 32; off > 0; off >>= 1) s += __shfl_down(s, off);
        if (lane == 0) out[b*CTXN + wv] = s + ev_b[wv];
    }
    if (tid < TLEN) out[BATCH*CTXN + b*TLEN + tid] = (tid == bidx) ? bestv : 0.f;
}

extern "C" void kernel_launch(void* const* d_in, const int* in_sizes, int n_in,
                              void* d_out, int out_size, void* d_ws, size_t ws_size,
                              hipStream_t stream) {
    const float* x      = (const float*)d_in[0];
    const float* proj_w = (const float*)d_in[1];
    const float* proj_b = (const float*)d_in[2];
    const float* conv_w = (const float*)d_in[3];
    const float* conv_b = (const float*)d_in[4];
    const float* ev_w   = (const float*)d_in[5];
    const float* ev_b   = (const float*)d_in[6];
    const float* sw_w   = (const float*)d_in[7];
    const float* sw_b   = (const float*)d_in[8];
    float* out = (float*)d_out;

    f16* wh  = (f16*)d_ws;
    f16* wlo = wh + WS_TOT;

    prep_weights<<<(WS_TOT + 255)/256, 256, 0, stream>>>(conv_w, proj_w, wh, wlo);

    (void)hipFuncSetAttribute((const void*)wavenet9,
                              hipFuncAttributeMaxDynamicSharedMemorySize, (int)LDS_BYTES);
    wavenet9<<<BATCH, 1024, LDS_BYTES, stream>>>(x, wh, wlo, proj_b, conv_b,
                                                 ev_w, ev_b, sw_w, sw_b, out);
}

// Round 6
// 553.155 us; speedup vs baseline: 1.4732x; 1.4732x over previous
//
#include <hip/hip_runtime.h>
#include <math.h>

// Fused WaveNet-ish encoder, v11: batch-paired blocks (2 batch elems / block).
// Theory: wall time tracks chip-wide weight re-fetch (wh+wlo = 5.25MB doesn't
// fit per-XCD L2; 256 blocks re-stream ~5MB each from L3 => ~1.3GB at
// ~3.3TB/s ~= 398us). v11 halves total weight traffic: 128 blocks, each
// computing TWO batch elements from one set of A-fragment loads (each A-load
// feeds 16 MFMAs instead of 8). Numerics identical to v8 (hi + lo*2^-5
// compensation, per-layer renorm) -> absmax should return to 4.88e-4.
// Spill guard: unroll-1 ks loops, transient-minimal bodies; WRITE_SIZE is
// the tripwire (must stay ~0.1MB).

#define BATCH 256
#define INCH  1024
#define HID   256
#define TLEN  128
#define CTXN  16
#define NLAY  8
#define LEAKF 0.2f
#define EPSF  1e-8f
#define SLO5  0.03125f   // 2^-5
#define SHI5  32.0f      // 2^5

typedef _Float16 f16;
typedef f16 f16x4 __attribute__((ext_vector_type(4)));
typedef f16 f16x8 __attribute__((ext_vector_type(8)));
typedef float f32x16 __attribute__((ext_vector_type(16)));

#define HT_STRIDE 264                    // halfs per row (528B, rows 16B-aligned)
#define HT_HALFS  (TLEN * HT_STRIDE)     // 33792
#define SCR_STRIDE 132
#define WS_CONV (NLAY*HID*2*HID)
#define WS_PROJ (HID*INCH)
#define WS_TOT  (WS_CONV + WS_PROJ)
// 2x Ht (f16) + scr[16][132] f32 + attn[2][128] f32 + redf[16] f32
#define LDS_BYTES (HT_HALFS*2*2 + (16*SCR_STRIDE + 2*TLEN + 16)*4)   // 144704

#define MFMA32(A,B,C) __builtin_amdgcn_mfma_f32_32x32x16_f16(A,B,C,0,0,0)
// swizzle: bits from t>>3 (intra-32 groups) AND t>>5 (staging quarter groups)
#define SW(t) (((((t)>>3)&3)<<3) ^ ((((t)>>5)&3)<<4))

static __device__ __forceinline__ f16x8 mul8(f16x8 v, f16 s) {
    f16x8 r;
    #pragma unroll
    for (int i = 0; i < 8; ++i) r[i] = v[i] * s;
    return r;
}

__global__ __launch_bounds__(256)
void prep_weights(const float* __restrict__ conv_w,
                  const float* __restrict__ proj_w,
                  f16* __restrict__ wh, f16* __restrict__ wlo)
{
    const int i = blockIdx.x * blockDim.x + threadIdx.x;
    if (i >= WS_TOT) return;
    float v; int dst;
    if (i < WS_CONV) {
        // src conv_w[l][o][ii][kk] -> dst [l][o][kk][ii]
        const int kk = i & 1, ii = (i >> 1) & (HID-1), o = (i >> 9) & (HID-1), l = i >> 17;
        v = conv_w[i];
        dst = ((l*HID + o)*2 + kk)*HID + ii;
    } else {
        v = proj_w[i - WS_CONV];
        dst = i;                         // proj [o][i] after conv region
    }
    const f16 hi = (f16)v;
    wh[dst]  = hi;
    wlo[dst] = (f16)((v - (float)hi) * SHI5);
}

__global__ __launch_bounds__(1024, 4)
void wavenet11(const float* __restrict__ x,
               const f16*   __restrict__ wh,
               const f16*   __restrict__ wlo,
               const float* __restrict__ proj_b,
               const float* __restrict__ conv_b,
               const float* __restrict__ ev_w,
               const float* __restrict__ ev_b,
               const float* __restrict__ sw_w,
               const float* __restrict__ sw_b,
               float* __restrict__ out)
{
    extern __shared__ char ldsb[];
    f16* const Ht0  = (f16*)ldsb;                    // batch 0: [128][264] swizzled
    f16* const Ht1  = Ht0 + HT_HALFS;                // batch 1
    float* scr  = (float*)(ldsb + HT_HALFS*2*2);     // [16][132]
    float* attn = scr + 16*SCR_STRIDE;               // [2][128]
    float* redf = attn + 2*TLEN;                     // [16]

    const int b0   = blockIdx.x * 2;                 // batches b0, b0+1
    const int tid  = threadIdx.x;
    const int lane = tid & 63;
    const int wv   = __builtin_amdgcn_readfirstlane(tid >> 6);  // 0..15
    const int mg   = wv & 7;           // o-tile: ob..ob+31
    const int ng   = wv >> 3;          // t-range: tb..tb+63 (2 n-tiles)
    const int ob   = mg << 5;
    const int tb   = ng << 6;
    const int col  = lane & 31;
    const int half = lane >> 5;

    f32x16 C[2][2];                    // [bt][nt]
    const f16x8 z8  = (f16x8)(f16)0.f;
    const f16   lo5 = (f16)SLO5;

    // ================= 1x1 projection 1024 -> 256 (both batches) ==========
    #pragma unroll
    for (int bt = 0; bt < 2; ++bt)
        #pragma unroll
        for (int nt = 0; nt < 2; ++nt) C[bt][nt] = (f32x16)0.f;

    const f16* ph = wh  + WS_CONV;
    const f16* pl = wlo + WS_CONV;
    const int sr = tid >> 2, stq = tid & 3;   // stage: row in chunk, t-quarter

    #pragma unroll 1
    for (int c = 0; c < 4; ++c) {
        if (c) __syncthreads();          // previous chunk's B-reads complete
        #pragma unroll
        for (int bt = 0; bt < 2; ++bt) {
            f16* const Hx = bt ? Ht1 : Ht0;
            const float* xr = x + (size_t)(b0 + bt) * INCH * TLEN
                                + (size_t)(c*256 + sr) * TLEN + stq*32;
            #pragma unroll
            for (int u = 0; u < 8; ++u) {
                const float4 v4 = *(const float4*)(xr + u*4);
                const float vv[4] = {v4.x, v4.y, v4.z, v4.w};
                #pragma unroll
                for (int e = 0; e < 4; ++e) {
                    const int t = stq*32 + u*4 + e;
                    const int p = t*HT_STRIDE + (((sr & ~7) ^ SW(t)) | (sr & 7));
                    Hx[p] = (f16)vv[e];
                }
            }
        }
        __syncthreads();
        #pragma unroll 1
        for (int ks = 0; ks < 16; ++ks) {
            const int kloc = ks*16 + half*8;
            const size_t ao = (size_t)(ob + col)*INCH + c*256 + kloc;
            const f16x8 Ah = *(const f16x8*)(ph + ao);
            const f16x8 Al = *(const f16x8*)(pl + ao);
            #pragma unroll
            for (int bt = 0; bt < 2; ++bt) {
                const f16* const Hx = bt ? Ht1 : Ht0;
                #pragma unroll
                for (int nt = 0; nt < 2; ++nt) {
                    const int t = tb + nt*32 + col;
                    const f16x8 Bh = *(const f16x8*)(Hx + t*HT_STRIDE + (kloc ^ SW(t)));
                    C[bt][nt] = MFMA32(Ah, Bh, C[bt][nt]);
                    C[bt][nt] = MFMA32(Al, mul8(Bh, lo5), C[bt][nt]);
                }
            }
        }
    }
    __syncthreads();   // all B-reads done; Ht free for h
    #pragma unroll
    for (int bt = 0; bt < 2; ++bt) {
        f16* const Hx = bt ? Ht1 : Ht0;
        #pragma unroll
        for (int nt = 0; nt < 2; ++nt) {
            const int t = tb + nt*32 + col;
            const int sw = SW(t);
            #pragma unroll
            for (int q = 0; q < 4; ++q) {
                const float4 bb = *(const float4*)(proj_b + ob + 8*q + 4*half);
                const float bv[4] = {bb.x, bb.y, bb.z, bb.w};
                f16x4 h4;
                #pragma unroll
                for (int s = 0; s < 4; ++s)
                    h4[s] = (f16)(C[bt][nt][q*4+s] + bv[s]);
                *(f16x4*)(Hx + t*HT_STRIDE + ((ob + 8*q) ^ sw) + 4*half) = h4;
            }
        }
    }
    __syncthreads();

    // ================= 8 dilated residual layers (in place) ==========
    #pragma unroll 1
    for (int l = 0; l < NLAY; ++l) {
        const int d = (l < 7) ? (1 << l) : 1;   // 1,2,4,8,16,32,64,1
        #pragma unroll
        for (int bt = 0; bt < 2; ++bt)
            #pragma unroll
            for (int nt = 0; nt < 2; ++nt) C[bt][nt] = (f32x16)0.f;
        const f16* wA = wh  + (size_t)l*HID*2*HID;   // [o][kk][256]
        const f16* wL = wlo + (size_t)l*HID*2*HID;
        int ro0[2], sw0[2], ro1[2], sw1[2]; bool oob1[2];
        #pragma unroll
        for (int nt = 0; nt < 2; ++nt) {
            const int t0 = tb + nt*32 + col;
            ro0[nt] = t0*HT_STRIDE; sw0[nt] = SW(t0);
            int r = t0 + d;
            oob1[nt] = r >= TLEN;
            if (oob1[nt]) r = TLEN-1;
            ro1[nt] = r*HT_STRIDE; sw1[nt] = SW(r);
        }
        const int abase = (ob + col)*2*HID + half*8;
        #pragma unroll 1
        for (int ks = 0; ks < 16; ++ks) {
            const int k = ks*16;
            const int kh = k + half*8;
            {   // ---- kk = 0 ----
                const f16x8 Ah = *(const f16x8*)(wA + abase + k);
                const f16x8 Al = *(const f16x8*)(wL + abase + k);
                #pragma unroll
                for (int bt = 0; bt < 2; ++bt) {
                    const f16* const Hx = bt ? Ht1 : Ht0;
                    #pragma unroll
                    for (int nt = 0; nt < 2; ++nt) {
                        const f16x8 Bh = *(const f16x8*)(Hx + ro0[nt] + (kh ^ sw0[nt]));
                        C[bt][nt] = MFMA32(Ah, Bh, C[bt][nt]);
                        C[bt][nt] = MFMA32(Al, mul8(Bh, lo5), C[bt][nt]);
                    }
                }
            }
            {   // ---- kk = 1 (shift +d, boundary-masked) ----
                const f16x8 Ah = *(const f16x8*)(wA + abase + HID + k);
                const f16x8 Al = *(const f16x8*)(wL + abase + HID + k);
                #pragma unroll
                for (int bt = 0; bt < 2; ++bt) {
                    const f16* const Hx = bt ? Ht1 : Ht0;
                    #pragma unroll
                    for (int nt = 0; nt < 2; ++nt) {
                        f16x8 Bh = *(const f16x8*)(Hx + ro1[nt] + (kh ^ sw1[nt]));
                        if (oob1[nt]) Bh = z8;
                        C[bt][nt] = MFMA32(Ah, Bh, C[bt][nt]);
                        C[bt][nt] = MFMA32(Al, mul8(Bh, lo5), C[bt][nt]);
                    }
                }
            }
        }
        // ---- epilogue: bias + leaky + skip + sumsq ----
        float ps[2][2] = {{0.f,0.f},{0.f,0.f}};
        #pragma unroll
        for (int bt = 0; bt < 2; ++bt) {
            const f16* const Hx = bt ? Ht1 : Ht0;
            #pragma unroll
            for (int nt = 0; nt < 2; ++nt) {
                const int t = tb + nt*32 + col;
                const int sw = SW(t);
                #pragma unroll
                for (int q = 0; q < 4; ++q) {
                    const float4 bb = *(const float4*)(conv_b + l*HID + ob + 8*q + 4*half);
                    const float bv[4] = {bb.x, bb.y, bb.z, bb.w};
                    const int p = t*HT_STRIDE + ((ob + 8*q) ^ sw) + 4*half;
                    const f16x4 sh = *(const f16x4*)(Hx + p);
                    #pragma unroll
                    for (int s = 0; s < 4; ++s) {
                        float y = C[bt][nt][q*4+s] + bv[s];
                        y = y > 0.f ? y : LEAKF * y;
                        const float v = y + (float)sh[s];
                        C[bt][nt][q*4+s] = v;
                        ps[bt][nt] = fmaf(v, v, ps[bt][nt]);
                    }
                }
            }
        }
        #pragma unroll
        for (int bt = 0; bt < 2; ++bt) {
            ps[bt][0] += __shfl_xor(ps[bt][0], 32);
            ps[bt][1] += __shfl_xor(ps[bt][1], 32);
        }
        if (lane < 32) {
            #pragma unroll
            for (int bt = 0; bt < 2; ++bt) {
                scr[(bt*8 + mg)*SCR_STRIDE + tb +      col] = ps[bt][0];
                scr[(bt*8 + mg)*SCR_STRIDE + tb + 32 + col] = ps[bt][1];
            }
        }
        __syncthreads();   // all conv/skip reads done + scr complete
        #pragma unroll
        for (int bt = 0; bt < 2; ++bt) {
            f16* const Hx = bt ? Ht1 : Ht0;
            #pragma unroll
            for (int nt = 0; nt < 2; ++nt) {
                const int t = tb + nt*32 + col;
                float s = 0.f;
                #pragma unroll
                for (int g = 0; g < 8; ++g) s += scr[(bt*8 + g)*SCR_STRIDE + t];
                const float inv = 1.f / (sqrtf(s) + EPSF);
                const int sw = SW(t);
                #pragma unroll
                for (int q = 0; q < 4; ++q) {
                    f16x4 h4;
                    #pragma unroll
                    for (int s2 = 0; s2 < 4; ++s2)
                        h4[s2] = (f16)(C[bt][nt][q*4+s2] * inv);
                    *(f16x4*)(Hx + t*HT_STRIDE + ((ob + 8*q) ^ sw) + 4*half) = h4;
                }
            }
        }
        __syncthreads();
    }

    // ================= switch head -> relu -> argmax (both batches) ========
    {
        const int bt = tid >> 9, t = tid & 127, og = (tid >> 7) & 3;
        const f16* const Hx = bt ? Ht1 : Ht0;
        const int sw = SW(t);
        float s = 0.f;
        #pragma unroll
        for (int q = 0; q < 8; ++q) {
            const int grp = og*64 + q*8;
            const f16x8 hv = *(const f16x8*)(Hx + t*HT_STRIDE + (grp ^ sw));
            const float* swp = sw_w + grp;
            #pragma unroll
            for (int j = 0; j < 8; ++j)
                s = fmaf(swp[j], (float)hv[j], s);
        }
        scr[(bt*4 + og)*SCR_STRIDE + t] = s;
    }
    __syncthreads();
    if (tid < 2*TLEN) {
        const int bt = tid >> 7, t = tid & 127;
        float s = sw_b[0];
        #pragma unroll
        for (int g = 0; g < 4; ++g) s += scr[(bt*4 + g)*SCR_STRIDE + t];
        attn[bt*TLEN + t] = fmaxf(s, 0.f);
    }
    __syncthreads();
    if (tid < 128) {           // wave 0 -> batch 0, wave 1 -> batch 1
        const int bt = tid >> 6;
        float v = attn[bt*TLEN + lane]; int bi = lane;
        const float v2 = attn[bt*TLEN + lane + 64];
        if (v2 > v) { v = v2; bi = lane + 64; }
        #pragma unroll
        for (int off = 32; off > 0; off >>= 1) {
            const float ov = __shfl_down(v, off);
            const int   oi = __shfl_down(bi, off);
            if (ov > v || (ov == v && oi < bi)) { v = ov; bi = oi; }
        }
        if (lane == 0) { redf[bt*2] = v; ((int*)redf)[bt*2 + 1] = bi; }
    }
    __syncthreads();

    #pragma unroll
    for (int bt = 0; bt < 2; ++bt) {
        const float bestv = redf[bt*2];
        const int   bidx  = ((const int*)redf)[bt*2 + 1];
        const int   swb   = SW(bidx);
        const f16* const Hx = bt ? Ht1 : Ht0;
        // event head: wave wv computes ctx=wv from h[:, bidx]
        float s = 0.f;
        #pragma unroll
        for (int q = 0; q < 4; ++q) {
            const int o = lane + 64*q;
            const int p = bidx*HT_STRIDE + (((o & ~7) ^ swb) | (o & 7));
            s = fmaf(ev_w[wv*HID + o], (float)Hx[p], s);
        }
        #pragma unroll
        for (int off = 32; off > 0; off >>= 1) s += __shfl_down(s, off);
        if (lane == 0) out[(b0 + bt)*CTXN + wv] = s + ev_b[wv];
    }
    if (tid < 2*TLEN) {
        const int bt = tid >> 7, t = tid & 127;
        const float bestv = redf[bt*2];
        const int   bidx  = ((const int*)redf)[bt*2 + 1];
        out[BATCH*CTXN + (b0 + bt)*TLEN + t] = (t == bidx) ? bestv : 0.f;
    }
}

extern "C" void kernel_launch(void* const* d_in, const int* in_sizes, int n_in,
                              void* d_out, int out_size, void* d_ws, size_t ws_size,
                              hipStream_t stream) {
    const float* x      = (const float*)d_in[0];
    const float* proj_w = (const float*)d_in[1];
    const float* proj_b = (const float*)d_in[2];
    const float* conv_w = (const float*)d_in[3];
    const float* conv_b = (const float*)d_in[4];
    const float* ev_w   = (const float*)d_in[5];
    const float* ev_b   = (const float*)d_in[6];
    const float* sw_w   = (const float*)d_in[7];
    const float* sw_b   = (const float*)d_in[8];
    float* out = (float*)d_out;

    f16* wh  = (f16*)d_ws;
    f16* wlo = wh + WS_TOT;

    prep_weights<<<(WS_TOT + 255)/256, 256, 0, stream>>>(conv_w, proj_w, wh, wlo);

    (void)hipFuncSetAttribute((const void*)wavenet11,
                              hipFuncAttributeMaxDynamicSharedMemorySize, (int)LDS_BYTES);
    wavenet11<<<BATCH/2, 1024, LDS_BYTES, stream>>>(x, wh, wlo, proj_b, conv_b,
                                                    ev_w, ev_b, sw_w, sw_b, out);
}